// Round 6
// baseline (205.410 us; speedup 1.0000x reference)
//
#include <hip/hip_runtime.h>
#include <type_traits>

typedef unsigned short ushort_t;
typedef float v4f __attribute__((ext_vector_type(4)));
typedef short v8s __attribute__((ext_vector_type(8)));
typedef unsigned short u16x8 __attribute__((ext_vector_type(8)));
typedef unsigned short u16x4v __attribute__((ext_vector_type(4)));

// Problem constants
#define NN    10000
#define NP    10048   // padded rows (157*64) so tile DMA never faults
#define EE    160000
#define FIN   512
#define NH    8
#define C1    30
#define HC1   240   // NH*C1 (original layer-1 width)
#define HC1P  256   // padded: 8 heads x 32 (head h at cols [32h, 32h+30))
#define C2    64
#define HC2   512   // NH*C2
#define NCLS  64
#define BUCK  64    // edge bucket capacity per dst (Poisson(16) max deg ~40, fixed seed)

#define TS1 (HC1P * FIN)   // w1t  [256][512]
#define TS2 (HC2 * HC1P)   // w2t  [512][256]
#define TS3 (NCLS * HC2)   // wlt  [64][512]
#define XS  (NN * FIN / 4) // x split work items (4 elems each)

#define GLOBAL_AS __attribute__((address_space(1)))
#define LDS_AS    __attribute__((address_space(3)))

// async global->LDS DMA: 16B per lane, dest = uniform base + 16*lane
__device__ __forceinline__ void async_cp16(const void* g, void* l) {
    __builtin_amdgcn_global_load_lds((const GLOBAL_AS unsigned int*)g,
                                     (LDS_AS unsigned int*)l, 16, 0, 0);
}

// ---------------- bf16 helpers ----------------

__device__ __forceinline__ void split1(float v, ushort_t& h, ushort_t& l) {
    unsigned u = __float_as_uint(v);
    unsigned rh = u + 0x7FFFu + ((u >> 16) & 1u);
    h = (ushort_t)(rh >> 16);
    float hf = __uint_as_float((unsigned)h << 16);
    float rem = v - hf;
    unsigned u2 = __float_as_uint(rem);
    unsigned rl = u2 + 0x7FFFu + ((u2 >> 16) & 1u);
    l = (ushort_t)(rl >> 16);
}

__device__ __forceinline__ ushort_t f2bf(float v) {
    unsigned u = __float_as_uint(v);
    return (ushort_t)((u + 0x7FFFu + ((u >> 16) & 1u)) >> 16);
}

__device__ __forceinline__ float bf2f(ushort_t u) {
    return __uint_as_float((unsigned)u << 16);
}

// ---------------- prep: zero counts + x split + weight transposes/splits + padded a1 ----------------

__global__ __launch_bounds__(256) void prep_kernel(
    const float* __restrict__ x,
    const float* __restrict__ W1, const float* __restrict__ W2,
    const float* __restrict__ Wl,
    const float* __restrict__ a1s, const float* __restrict__ a1d,
    ushort_t* __restrict__ xh, ushort_t* __restrict__ xl,
    ushort_t* __restrict__ t1h, ushort_t* __restrict__ t1l,
    ushort_t* __restrict__ t2h, ushort_t* __restrict__ t2l,
    ushort_t* __restrict__ t3h, ushort_t* __restrict__ t3l,
    float* __restrict__ a1sP, float* __restrict__ a1dP,
    int* __restrict__ counts) {
    int idx = blockIdx.x * 256 + threadIdx.x;
    if (idx < NN) counts[idx] = 0;   // consumed by GEMM1's embedded scatter (next dispatch)
    if (idx < XS) {
        // split x into hi/lo bf16 (4 elems/thread, contiguous)
        int i = idx << 2;
        float4 v = *(const float4*)(x + i);
        ushort_t h, l;
        u16x4v hh, ll;
        split1(v.x, h, l); hh[0] = h; ll[0] = l;
        split1(v.y, h, l); hh[1] = h; ll[1] = l;
        split1(v.z, h, l); hh[2] = h; ll[2] = l;
        split1(v.w, h, l); hh[3] = h; ll[3] = l;
        *(u16x4v*)(xh + i) = hh;
        *(u16x4v*)(xl + i) = ll;
        return;
    }
    idx -= XS;
    if (idx < TS1) {
        int n = idx >> 9, k = idx & 511;
        int cc = n & 31;
        float v = (cc < 30) ? W1[(size_t)k * HC1 + ((n >> 5) * 30 + cc)] : 0.f;
        ushort_t h, l;
        split1(v, h, l);
        t1h[idx] = h;
        t1l[idx] = l;
    } else if (idx < TS1 + TS2) {
        int lo = idx - TS1;
        int n = lo >> 8, k = lo & 255;
        int cc = k & 31;
        float v = (cc < 30) ? W2[(size_t)((k >> 5) * 30 + cc) * HC2 + n] : 0.f;
        ushort_t h, l;
        split1(v, h, l);
        t2h[lo] = h;
        t2l[lo] = l;
    } else if (idx < TS1 + TS2 + TS3) {
        int lo = idx - TS1 - TS2;
        int n = lo >> 9, k = lo & 511;
        float v = Wl[(size_t)k * NCLS + n];
        ushort_t h, l;
        split1(v, h, l);
        t3h[lo] = h;
        t3l[lo] = l;
    } else if (idx < TS1 + TS2 + TS3 + 2 * HC1P) {
        int j = idx - (TS1 + TS2 + TS3);
        int c = j & (HC1P - 1);
        int cc = c & 31;
        float vs = (cc < 30) ? a1s[(c >> 5) * 30 + cc] : 0.f;
        float vd = (cc < 30) ? a1d[(c >> 5) * 30 + cc] : 0.f;
        if (j < HC1P) a1sP[c] = vs;
        else          a1dP[c] = vd;
    }
}

// ---------------- split-bf16 MFMA GEMM (DMA-staged, double-buffered) ----------------
// R1 inner structure; R6: SMALL TILES for occupancy. GEMM grids were 314-628 blocks
// = 1.2-2.5 blocks/CU -> barrier drains had no co-resident waves to hide behind
// (latency-starved). TM=1 tiles give 1256 blocks (~4.9/CU, ~20 waves/CU).
// A,B pre-transposed/split bf16 hi/lo [rows][K]. Tile (32*TM) x (32*TN), BK=32,
// 256 threads = 4 waves (2x2). LDS: unpadded 64B rows, chunk-XOR swizzle on the
// per-lane GLOBAL source (linear LDS dest, rule #21), same XOR on fragment reads.
// 2-phase pipeline: stage(next buf) before ds_read+MFMA; ONE barrier/K-step.
// TPH>0: fused attention scores; head spans 16*TPH cols (needs TN % TPH == 0).
// SCAT: embedded bucket scatter rides in the prologue-DMA latency shadow.

template <int TM, int TN, bool BIAS, bool WF32, bool WBF, int TPH, bool SCAT>
__global__ __launch_bounds__(256) void gemm_mfma(const ushort_t* __restrict__ Ath,
                                                 const ushort_t* __restrict__ Atl,
                                                 const ushort_t* __restrict__ Bth,
                                                 const ushort_t* __restrict__ Btl,
                                                 const float* __restrict__ bias,
                                                 float* __restrict__ C,
                                                 ushort_t* __restrict__ Cbf,
                                                 const float* __restrict__ att_s,
                                                 const float* __restrict__ att_d,
                                                 float* __restrict__ asrc,
                                                 float* __restrict__ adst,
                                                 const int* __restrict__ srcE,
                                                 const int* __restrict__ dstE,
                                                 int* __restrict__ cnt,
                                                 int* __restrict__ eslot,
                                                 int M, int K, int CS) {
    constexpr int ROWS = 32 * TM;
    constexpr int BN   = 32 * TN;
    constexpr int CA = ROWS / 16;          // 1KB chunks per A table per K-step
    constexpr int CB = BN / 16;
    constexpr int TOT = 2 * (CA + CB);
    static_assert(TOT % 4 == 0, "chunks must split across 4 waves");
    constexpr int PW = TOT / 4;            // chunks per wave
    constexpr int AOFF_L = ROWS * 32;      // short offsets within a buffer
    constexpr int BOFF_H = ROWS * 64;
    constexpr int BOFF_L = ROWS * 64 + BN * 32;
    constexpr int BUFSZ  = (ROWS + BN) * 64;
    __shared__ ushort_t lds[2][BUFSZ];

    const int t    = threadIdx.x;
    const int lane = t & 63;
    const int wave = t >> 6;
    const int quad = lane >> 4;
    const int l16  = lane & 15;
    const int wm   = wave >> 1;
    const int wn   = wave & 1;
    const int bm   = blockIdx.x * ROWS;
    const int bn   = blockIdx.y * BN;

    // --- staging descriptors (per-lane global source, uniform LDS dest) ---
    const ushort_t* gsrc[PW];
    int ldst[PW];
    {
        const int rr = lane >> 2;          // row within 16-row chunk
        const int q  = lane & 3;           // 16B slot within 64B row
        const int sw = (q ^ (rr & 3)) << 3;  // inverse-swizzled source chunk (shorts)
        #pragma unroll
        for (int c = 0; c < PW; ++c) {
            int j = wave * PW + c;
            const ushort_t* gt;
            int off, jj, gb;
            if (j < CA)               { gt = Ath; jj = j;              off = 0;      gb = bm; }
            else if (j < 2 * CA)      { gt = Atl; jj = j - CA;         off = AOFF_L; gb = bm; }
            else if (j < 2 * CA + CB) { gt = Bth; jj = j - 2 * CA;     off = BOFF_H; gb = bn; }
            else                      { gt = Btl; jj = j - 2 * CA - CB; off = BOFF_L; gb = bn; }
            gsrc[c] = gt + (size_t)(gb + jj * 16 + rr) * K + sw;
            ldst[c] = off + jj * 512;      // 1KB = 512 shorts per chunk
        }
    }

    // --- fragment read offsets (swizzled) ---
    int aoff[TM], boff[TN];
    #pragma unroll
    for (int tt = 0; tt < TM; ++tt) {
        int r = wm * 16 * TM + tt * 16 + l16;
        aoff[tt] = r * 32 + ((quad ^ (r & 3)) << 3);
    }
    #pragma unroll
    for (int tn = 0; tn < TN; ++tn) {
        int r = wn * 16 * TN + tn * 16 + l16;
        boff[tn] = r * 32 + ((quad ^ (r & 3)) << 3);
    }

    v4f acc[TM][TN];
    #pragma unroll
    for (int i = 0; i < TM; ++i)
        #pragma unroll
        for (int j = 0; j < TN; ++j) acc[i][j] = 0.f;

    // prologue: stage first K-step into buf 0
    #pragma unroll
    for (int c = 0; c < PW; ++c) async_cp16(gsrc[c], &lds[0][ldst[c]]);

    // embedded bucket scatter: rides in the prologue-DMA latency shadow
    if constexpr (SCAT) {
        const int tid0 = (blockIdx.y * gridDim.x + blockIdx.x) * 256 + t;
        const int tots = gridDim.x * gridDim.y * 256;
        for (int e = tid0; e < EE; e += tots) {
            int d = dstE[e];
            int pos = atomicAdd(&cnt[d], 1);
            if (pos < BUCK) eslot[d * BUCK + pos] = srcE[e];
        }
    }

    int cur = 0;
    for (int k0 = 0; k0 < K; k0 += 32) {
        __syncthreads();  // drains vmcnt(0): buf[cur] ready; all reads of buf[cur^1] done
        if (k0 + 32 < K) {
            #pragma unroll
            for (int c = 0; c < PW; ++c)
                async_cp16(gsrc[c] + k0 + 32, &lds[cur ^ 1][ldst[c]]);
        }
        const ushort_t* bufc = lds[cur];
        v8s ah[TM], al2[TM], bh2[TN], bl2[TN];
        #pragma unroll
        for (int tt = 0; tt < TM; ++tt) {
            ah[tt]  = *(const v8s*)&bufc[aoff[tt]];
            al2[tt] = *(const v8s*)&bufc[AOFF_L + aoff[tt]];
        }
        #pragma unroll
        for (int tn = 0; tn < TN; ++tn) {
            bh2[tn] = *(const v8s*)&bufc[BOFF_H + boff[tn]];
            bl2[tn] = *(const v8s*)&bufc[BOFF_L + boff[tn]];
        }
        #pragma unroll
        for (int tm = 0; tm < TM; ++tm)
            #pragma unroll
            for (int tn = 0; tn < TN; ++tn) {
                acc[tm][tn] = __builtin_amdgcn_mfma_f32_16x16x32_bf16(
                    ah[tm], bh2[tn], acc[tm][tn], 0, 0, 0);
                acc[tm][tn] = __builtin_amdgcn_mfma_f32_16x16x32_bf16(
                    ah[tm], bl2[tn], acc[tm][tn], 0, 0, 0);
                acc[tm][tn] = __builtin_amdgcn_mfma_f32_16x16x32_bf16(
                    al2[tm], bh2[tn], acc[tm][tn], 0, 0, 0);
            }
        cur ^= 1;
    }

    // epilogue: C/D layout col=lane&15, row=quad*4+reg
    #pragma unroll
    for (int tm = 0; tm < TM; ++tm) {
        #pragma unroll
        for (int tn = 0; tn < TN; ++tn) {
            int row0 = bm + wm * 16 * TM + tm * 16 + quad * 4;
            int col  = bn + wn * 16 * TN + tn * 16 + l16;
            float badd = BIAS ? bias[col] : 0.f;
            #pragma unroll
            for (int reg = 0; reg < 4; ++reg) {
                int row = row0 + reg;
                if (row < M) {
                    float v = acc[tm][tn][reg] + badd;
                    if (WF32) C[(size_t)row * CS + col] = v;
                    if (WBF) Cbf[(size_t)row * CS + col] = f2bf(v);
                }
            }
        }
    }

    // fused attention scores: head spans 16*TPH contiguous cols
    if constexpr (TPH > 0) {
        constexpr int GR = TN / TPH;
        float aS[TN], aD[TN];
        #pragma unroll
        for (int tn = 0; tn < TN; ++tn) {
            int col = bn + wn * 16 * TN + tn * 16 + l16;
            aS[tn] = att_s[col];
            aD[tn] = att_d[col];
        }
        #pragma unroll
        for (int tm = 0; tm < TM; ++tm) {
            #pragma unroll
            for (int reg = 0; reg < 4; ++reg) {
                #pragma unroll
                for (int g = 0; g < GR; ++g) {
                    float ss = 0.f, sd = 0.f;
                    #pragma unroll
                    for (int ti = 0; ti < TPH; ++ti) {
                        int tn = g * TPH + ti;
                        ss += acc[tm][tn][reg] * aS[tn];
                        sd += acc[tm][tn][reg] * aD[tn];
                    }
                    #pragma unroll
                    for (int off = 1; off < 16; off <<= 1) {
                        ss += __shfl_xor(ss, off);
                        sd += __shfl_xor(sd, off);
                    }
                    if (l16 == 0) {
                        int row = bm + wm * 16 * TM + tm * 16 + quad * 4 + reg;
                        if (row < M) {
                            int head = (bn + wn * 16 * TN + g * 16 * TPH) / (16 * TPH);
                            asrc[row * NH + head] = ss;
                            adst[row * NH + head] = sd;
                        }
                    }
                }
            }
        }
    }
}

// ---------------- unified fused softmax aggregation ----------------
// 1 wave / dst node, CPL channels/lane (row = 64*CPL chans, head = lane>>3).
// Online softmax, depth-1 prefetch over 4-edge groups.
// Edge list: padded bucket edge_slot[d*BUCK .. d*BUCK+deg), deg = counts[d].
// OSPLIT: write split hi/lo bf16.  OF32: write fp32.  PADB: padded bias map.

template <int CPL, bool ELU, bool OSPLIT, bool OF32, bool PADB>
__global__ __launch_bounds__(256) void agg_u(const ushort_t* __restrict__ hb,
                                             const float* __restrict__ asrc,
                                             const float* __restrict__ adst,
                                             const int* __restrict__ counts,
                                             const int* __restrict__ edge_slot,
                                             const float* __restrict__ bias,
                                             float* __restrict__ outf,
                                             ushort_t* __restrict__ outh,
                                             ushort_t* __restrict__ outl,
                                             int n) {
    constexpr int RSB = CPL * 64;
    using VT = typename std::conditional<CPL == 8, u16x8, u16x4v>::type;
    const int d    = (blockIdx.x * blockDim.x + threadIdx.x) >> 6;
    const int lane = threadIdx.x & 63;
    if (d >= n) return;
    const int head = lane >> 3;

    const float adh = (lane < NH) ? adst[d * NH + lane] : 0.f;

    float m, s;
    float ac[CPL];
    {
        float a = (lane < NH) ? asrc[d * NH + lane] + adh : 0.f;
        a = fmaxf(a, 0.2f * a);
        m = a;
        s = 1.f;
        VT u = *(const VT*)(hb + (size_t)d * RSB + CPL * lane);
        #pragma unroll
        for (int i = 0; i < CPL; ++i) ac[i] = bf2f(u[i]);
    }

    const int beg = d * BUCK;
    const int end = beg + min(counts[d], BUCK);

    auto LD = [&](int eb, VT* rr, float* ss) {
        int i0 = edge_slot[eb], i1 = edge_slot[eb + 1];
        int i2 = edge_slot[eb + 2], i3 = edge_slot[eb + 3];
        rr[0] = *(const VT*)(hb + (size_t)i0 * RSB + CPL * lane);
        rr[1] = *(const VT*)(hb + (size_t)i1 * RSB + CPL * lane);
        rr[2] = *(const VT*)(hb + (size_t)i2 * RSB + CPL * lane);
        rr[3] = *(const VT*)(hb + (size_t)i3 * RSB + CPL * lane);
        if (lane < NH) {
            ss[0] = asrc[i0 * NH + lane];
            ss[1] = asrc[i1 * NH + lane];
            ss[2] = asrc[i2 * NH + lane];
            ss[3] = asrc[i3 * NH + lane];
        } else {
            ss[0] = ss[1] = ss[2] = ss[3] = 0.f;
        }
    };
    auto PR = [&](const VT* rr, const float* ss) {
        float a0 = ss[0] + adh, a1 = ss[1] + adh, a2 = ss[2] + adh, a3 = ss[3] + adh;
        a0 = fmaxf(a0, 0.2f * a0);
        a1 = fmaxf(a1, 0.2f * a1);
        a2 = fmaxf(a2, 0.2f * a2);
        a3 = fmaxf(a3, 0.2f * a3);
        float mn = fmaxf(m, fmaxf(fmaxf(a0, a1), fmaxf(a2, a3)));
        float al = __expf(m - mn);
        float w0 = __expf(a0 - mn);
        float w1 = __expf(a1 - mn);
        float w2 = __expf(a2 - mn);
        float w3 = __expf(a3 - mn);
        s = s * al + (w0 + w1) + (w2 + w3);
        m = mn;
        float alc = __shfl(al, head);
        float c0 = __shfl(w0, head);
        float c1 = __shfl(w1, head);
        float c2 = __shfl(w2, head);
        float c3 = __shfl(w3, head);
        #pragma unroll
        for (int i = 0; i < CPL; ++i)
            ac[i] = ac[i] * alc + c0 * bf2f(rr[0][i]) + c1 * bf2f(rr[1][i]) +
                    c2 * bf2f(rr[2][i]) + c3 * bf2f(rr[3][i]);
    };

    int e = beg;
    const int ng = (end - beg) >> 2;
    if (ng > 0) {
        VT cr[4];
        float cs[4];
        LD(e, cr, cs);
        for (int g = 1; g < ng; ++g) {
            VT nr[4];
            float ns[4];
            LD(e + 4 * g, nr, ns);
            PR(cr, cs);
            #pragma unroll
            for (int j = 0; j < 4; ++j) { cr[j] = nr[j]; cs[j] = ns[j]; }
        }
        PR(cr, cs);
        e += 4 * ng;
    }
    for (; e < end; ++e) {
        int i0 = edge_slot[e];
        VT r0 = *(const VT*)(hb + (size_t)i0 * RSB + CPL * lane);
        float a0 = (lane < NH) ? asrc[i0 * NH + lane] + adh : 0.f;
        a0 = fmaxf(a0, 0.2f * a0);
        float mn = fmaxf(m, a0);
        float al = __expf(m - mn);
        float w0 = __expf(a0 - mn);
        s = s * al + w0;
        m = mn;
        float alc = __shfl(al, head);
        float c0w = __shfl(w0, head);
        #pragma unroll
        for (int i = 0; i < CPL; ++i) ac[i] = ac[i] * alc + c0w * bf2f(r0[i]);
    }

    float inv = 1.f / s;
    float ivc = __shfl(inv, head);
    float o[CPL];
    if constexpr (PADB) {
        const int c = CPL * lane;
        const int cc = c & 31;
        const int bbase = (c >> 5) * 30 + cc;
        #pragma unroll
        for (int i = 0; i < CPL; ++i) {
            float b = (cc + i < 30) ? bias[bbase + i] : 0.f;
            o[i] = ac[i] * ivc + b;   // pad channels: 0*ivc + 0 = 0
        }
    } else {
        #pragma unroll
        for (int i = 0; i < CPL; ++i) o[i] = ac[i] * ivc + bias[CPL * lane + i];
    }
    if (ELU) {
        #pragma unroll
        for (int i = 0; i < CPL; ++i) o[i] = (o[i] > 0.f) ? o[i] : __expf(o[i]) - 1.f;
    }
    if constexpr (OSPLIT) {
        VT hh, ll;
        #pragma unroll
        for (int i = 0; i < CPL; ++i) {
            ushort_t h2, l2;
            split1(o[i], h2, l2);
            hh[i] = h2;
            ll[i] = l2;
        }
        *(VT*)(outh + (size_t)d * RSB + CPL * lane) = hh;
        *(VT*)(outl + (size_t)d * RSB + CPL * lane) = ll;
    }
    if constexpr (OF32) {
        float4* orow = (float4*)(outf + (size_t)d * RSB);
        #pragma unroll
        for (int q = 0; q < CPL / 4; ++q) {
            float4 v;
            v.x = o[4 * q + 0];
            v.y = o[4 * q + 1];
            v.z = o[4 * q + 2];
            v.w = o[4 * q + 3];
            orow[(CPL / 4) * lane + q] = v;
        }
    }
}

// ---------------- launch ----------------

extern "C" void kernel_launch(void* const* d_in, const int* in_sizes, int n_in,
                              void* d_out, int out_size, void* d_ws, size_t ws_size,
                              hipStream_t stream) {
    const float* x      = (const float*)d_in[0];
    const int*   eidx   = (const int*)d_in[1];   // [2, E]
    const float* W1     = (const float*)d_in[2];
    const float* a1_src = (const float*)d_in[3];
    const float* a1_dst = (const float*)d_in[4];
    const float* b1     = (const float*)d_in[5];
    const float* W2     = (const float*)d_in[6];
    const float* a2_src = (const float*)d_in[7];
    const float* a2_dst = (const float*)d_in[8];
    const float* b2     = (const float*)d_in[9];
    const float* Wlin   = (const float*)d_in[10];
    const float* blin   = (const float*)d_in[11];

    const int* src = eidx;        // row 0
    const int* dst = eidx + EE;   // row 1

    float* out0  = (float*)d_out;                      // [N, NCLS]
    float* h_out = (float*)d_out + (size_t)NN * NCLS;  // [N, HC2] (output 1)

    // workspace layout: floats, then ushorts, then ints
    float* f = (float*)d_ws;
    float* asrc1 = f;
    float* adst1 = asrc1 + NN * NH;
    float* asrc2 = adst1 + NN * NH;
    float* adst2 = asrc2 + NN * NH;
    float* a1sP  = adst2 + NN * NH;          // [HC1P]
    float* a1dP  = a1sP + HC1P;              // [HC1P]
    ushort_t* xh    = (ushort_t*)(a1dP + HC1P);        // [NP][FIN] hi
    ushort_t* xl    = xh + (size_t)NP * FIN;           // [NP][FIN] lo
    ushort_t* w1t_h = xl + (size_t)NP * FIN;
    ushort_t* w1t_l = w1t_h + TS1;
    ushort_t* w2t_h = w1t_l + TS1;
    ushort_t* w2t_l = w2t_h + TS2;
    ushort_t* wlt_h = w2t_l + TS2;
    ushort_t* wlt_l = wlt_h + TS3;
    ushort_t* h1p_bf = wlt_l + TS3;                    // [NN][HC1P] bf16 (pre-agg)
    ushort_t* h1h    = h1p_bf + (size_t)NN * HC1P;     // [NP][HC1P] hi (post-agg)
    ushort_t* h1l    = h1h + (size_t)NP * HC1P;        // [NP][HC1P] lo
    ushort_t* h2p_bf = h1l + (size_t)NP * HC1P;        // [NN][HC2] bf16 (pre-agg)
    ushort_t* h2h    = h2p_bf + (size_t)NN * HC2;      // [NP][HC2] hi (post-agg)
    ushort_t* h2l    = h2h + (size_t)NP * HC2;         // [NP][HC2] lo
    int* counts    = (int*)(h2l + (size_t)NP * HC2);   // [NN] degree/cursor
    int* edge_slot = counts + NN;                      // [NN*BUCK] padded buckets

    // prep: zero counts + x split + transposes/splits + padded a1 vectors
    {
        const int total = XS + TS1 + TS2 + TS3 + 2 * HC1P;
        prep_kernel<<<(total + 255) / 256, 256, 0, stream>>>(
            x, W1, W2, Wlin, a1_src, a1_dst, xh, xl, w1t_h, w1t_l,
            w2t_h, w2t_l, wlt_h, wlt_l, a1sP, a1dP, counts);
    }

    const int MB32 = NP / 32;  // 314 row-tiles of 32

    // Layer 1: 32x64 tiles -> grid(314,4)=1256 blocks (~4.9/CU) + att1 + EMBEDDED scatter
    {
        dim3 grid(MB32, HC1P / 64);
        gemm_mfma<1, 2, false, false, true, 2, true><<<grid, 256, 0, stream>>>(
            xh, xl, w1t_h, w1t_l, nullptr, nullptr, h1p_bf,
            a1sP, a1dP, asrc1, adst1, src, dst, counts, edge_slot,
            NN, FIN, HC1P);
    }
    // agg1: 4 ch/lane, ELU, writes split hi/lo bf16 h1
    agg_u<4, true, true, false, true><<<(NN + 3) / 4, 256, 0, stream>>>(
        h1p_bf, asrc1, adst1, counts, edge_slot, b1, nullptr, h1h, h1l, NN);

    // Layer 2: 32x128 tiles -> grid(314,4)=1256 blocks + att2 (head=64 cols needs TN=4)
    {
        dim3 grid(MB32, HC2 / 128);
        gemm_mfma<1, 4, false, false, true, 4, false><<<grid, 256, 0, stream>>>(
            h1h, h1l, w2t_h, w2t_l, nullptr, nullptr, h2p_bf,
            a2_src, a2_dst, asrc2, adst2, nullptr, nullptr, nullptr, nullptr,
            NN, HC1P, HC2);
    }
    // agg2: 8 ch/lane, no ELU, writes fp32 h_out (output 1) + split hi/lo for head GEMM
    agg_u<8, false, true, true, false><<<(NN + 3) / 4, 256, 0, stream>>>(
        h2p_bf, asrc2, adst2, counts, edge_slot, b2, h_out, h2h, h2l, NN);

    // Head: 32x32 tiles -> grid(313,2)=626 blocks
    {
        dim3 grid((NN + 31) / 32, NCLS / 32);
        gemm_mfma<1, 1, true, true, false, 0, false><<<grid, 256, 0, stream>>>(
            h2h, h2l, wlt_h, wlt_l, blin, out0, nullptr,
            nullptr, nullptr, nullptr, nullptr, nullptr, nullptr, nullptr, nullptr,
            NN, HC2, NCLS);
    }
}

// Round 7
// 196.994 us; speedup vs baseline: 1.0427x; 1.0427x over previous
//
#include <hip/hip_runtime.h>
#include <type_traits>

typedef unsigned short ushort_t;
typedef float v4f __attribute__((ext_vector_type(4)));
typedef short v8s __attribute__((ext_vector_type(8)));
typedef unsigned short u16x8 __attribute__((ext_vector_type(8)));
typedef unsigned short u16x4v __attribute__((ext_vector_type(4)));

// Problem constants
#define NN    10000
#define NP    10048   // padded rows (157*64) so tile DMA never faults
#define EE    160000
#define FIN   512
#define NH    8
#define C1    30
#define HC1   240   // NH*C1 (original layer-1 width)
#define HC1P  256   // padded: 8 heads x 32 (head h at cols [32h, 32h+30))
#define C2    64
#define HC2   512   // NH*C2
#define NCLS  64
#define BUCK  64    // edge bucket capacity per dst (Poisson(16) max deg ~40, fixed seed)

#define TS1 (HC1P * FIN)   // w1t  [256][512]
#define TS2 (HC2 * HC1P)   // w2t  [512][256]
#define TS3 (NCLS * HC2)   // wlt  [64][512]
#define XS  (NN * FIN / 4) // x split work items (4 elems each)

#define GLOBAL_AS __attribute__((address_space(1)))
#define LDS_AS    __attribute__((address_space(3)))

// async global->LDS DMA: 16B per lane, dest = uniform base + 16*lane
__device__ __forceinline__ void async_cp16(const void* g, void* l) {
    __builtin_amdgcn_global_load_lds((const GLOBAL_AS unsigned int*)g,
                                     (LDS_AS unsigned int*)l, 16, 0, 0);
}

// ---------------- bf16 helpers ----------------

__device__ __forceinline__ void split1(float v, ushort_t& h, ushort_t& l) {
    unsigned u = __float_as_uint(v);
    unsigned rh = u + 0x7FFFu + ((u >> 16) & 1u);
    h = (ushort_t)(rh >> 16);
    float hf = __uint_as_float((unsigned)h << 16);
    float rem = v - hf;
    unsigned u2 = __float_as_uint(rem);
    unsigned rl = u2 + 0x7FFFu + ((u2 >> 16) & 1u);
    l = (ushort_t)(rl >> 16);
}

__device__ __forceinline__ ushort_t f2bf(float v) {
    unsigned u = __float_as_uint(v);
    return (ushort_t)((u + 0x7FFFu + ((u >> 16) & 1u)) >> 16);
}

__device__ __forceinline__ float bf2f(ushort_t u) {
    return __uint_as_float((unsigned)u << 16);
}

// ---------------- prep: zero counts + x split + weight transposes/splits + padded a1 ----------------

__global__ __launch_bounds__(256) void prep_kernel(
    const float* __restrict__ x,
    const float* __restrict__ W1, const float* __restrict__ W2,
    const float* __restrict__ Wl,
    const float* __restrict__ a1s, const float* __restrict__ a1d,
    ushort_t* __restrict__ xh, ushort_t* __restrict__ xl,
    ushort_t* __restrict__ t1h, ushort_t* __restrict__ t1l,
    ushort_t* __restrict__ t2h, ushort_t* __restrict__ t2l,
    ushort_t* __restrict__ t3h, ushort_t* __restrict__ t3l,
    float* __restrict__ a1sP, float* __restrict__ a1dP,
    int* __restrict__ counts) {
    int idx = blockIdx.x * 256 + threadIdx.x;
    if (idx < NN) counts[idx] = 0;   // consumed by GEMM1's embedded scatter (next dispatch)
    if (idx < XS) {
        // split x into hi/lo bf16 (4 elems/thread, contiguous)
        int i = idx << 2;
        float4 v = *(const float4*)(x + i);
        ushort_t h, l;
        u16x4v hh, ll;
        split1(v.x, h, l); hh[0] = h; ll[0] = l;
        split1(v.y, h, l); hh[1] = h; ll[1] = l;
        split1(v.z, h, l); hh[2] = h; ll[2] = l;
        split1(v.w, h, l); hh[3] = h; ll[3] = l;
        *(u16x4v*)(xh + i) = hh;
        *(u16x4v*)(xl + i) = ll;
        return;
    }
    idx -= XS;
    if (idx < TS1) {
        int n = idx >> 9, k = idx & 511;
        int cc = n & 31;
        float v = (cc < 30) ? W1[(size_t)k * HC1 + ((n >> 5) * 30 + cc)] : 0.f;
        ushort_t h, l;
        split1(v, h, l);
        t1h[idx] = h;
        t1l[idx] = l;
    } else if (idx < TS1 + TS2) {
        int lo = idx - TS1;
        int n = lo >> 8, k = lo & 255;
        int cc = k & 31;
        float v = (cc < 30) ? W2[(size_t)((k >> 5) * 30 + cc) * HC2 + n] : 0.f;
        ushort_t h, l;
        split1(v, h, l);
        t2h[lo] = h;
        t2l[lo] = l;
    } else if (idx < TS1 + TS2 + TS3) {
        int lo = idx - TS1 - TS2;
        int n = lo >> 9, k = lo & 511;
        float v = Wl[(size_t)k * NCLS + n];
        ushort_t h, l;
        split1(v, h, l);
        t3h[lo] = h;
        t3l[lo] = l;
    } else if (idx < TS1 + TS2 + TS3 + 2 * HC1P) {
        int j = idx - (TS1 + TS2 + TS3);
        int c = j & (HC1P - 1);
        int cc = c & 31;
        float vs = (cc < 30) ? a1s[(c >> 5) * 30 + cc] : 0.f;
        float vd = (cc < 30) ? a1d[(c >> 5) * 30 + cc] : 0.f;
        if (j < HC1P) a1sP[c] = vs;
        else          a1dP[c] = vd;
    }
}

// ---------------- split-bf16 MFMA GEMM (DMA-staged, double-buffered) ----------------
// R5 config (best measured 200.5us). A,B pre-transposed/split bf16 hi/lo [rows][K].
// Tile (32*TM) x (32*TN), BK=32, 256 threads = 4 waves (2x2 wave grid).
// LDS: unpadded 64B rows, chunk-XOR swizzle (slot = quad ^ (row&3)) applied to the
// per-lane GLOBAL source address at stage time (linear LDS dest, rule #21) and the
// same XOR on fragment reads -> 2-way bank aliasing (free).
// 2-phase pipeline: stage(next buf) issued before ds_read+MFMA; ONE barrier/K-step.
// TPH>0: fused attention scores; head spans 16*TPH cols (needs TN % TPH == 0).
// SCAT: embedded bucket scatter rides in the prologue-DMA latency shadow.
// NOTE (R6 lesson): smaller tiles (TM=1) for occupancy REGRESSED (+5us) — the
// barrier drain was already TLP-covered; keep TM=2 tiles.

template <int TM, int TN, bool BIAS, bool WF32, bool WBF, int TPH, bool SCAT>
__global__ __launch_bounds__(256) void gemm_mfma(const ushort_t* __restrict__ Ath,
                                                 const ushort_t* __restrict__ Atl,
                                                 const ushort_t* __restrict__ Bth,
                                                 const ushort_t* __restrict__ Btl,
                                                 const float* __restrict__ bias,
                                                 float* __restrict__ C,
                                                 ushort_t* __restrict__ Cbf,
                                                 const float* __restrict__ att_s,
                                                 const float* __restrict__ att_d,
                                                 float* __restrict__ asrc,
                                                 float* __restrict__ adst,
                                                 const int* __restrict__ srcE,
                                                 const int* __restrict__ dstE,
                                                 int* __restrict__ cnt,
                                                 int* __restrict__ eslot,
                                                 int M, int K, int CS) {
    constexpr int ROWS = 32 * TM;
    constexpr int BN   = 32 * TN;
    constexpr int CA = ROWS / 16;          // 1KB chunks per A table per K-step
    constexpr int CB = BN / 16;
    constexpr int TOT = 2 * (CA + CB);
    static_assert(TOT % 4 == 0, "chunks must split across 4 waves");
    constexpr int PW = TOT / 4;            // chunks per wave
    constexpr int AOFF_L = ROWS * 32;      // short offsets within a buffer
    constexpr int BOFF_H = ROWS * 64;
    constexpr int BOFF_L = ROWS * 64 + BN * 32;
    constexpr int BUFSZ  = (ROWS + BN) * 64;
    __shared__ ushort_t lds[2][BUFSZ];

    const int t    = threadIdx.x;
    const int lane = t & 63;
    const int wave = t >> 6;
    const int quad = lane >> 4;
    const int l16  = lane & 15;
    const int wm   = wave >> 1;
    const int wn   = wave & 1;
    const int bm   = blockIdx.x * ROWS;
    const int bn   = blockIdx.y * BN;

    // --- staging descriptors (per-lane global source, uniform LDS dest) ---
    const ushort_t* gsrc[PW];
    int ldst[PW];
    {
        const int rr = lane >> 2;          // row within 16-row chunk
        const int q  = lane & 3;           // 16B slot within 64B row
        const int sw = (q ^ (rr & 3)) << 3;  // inverse-swizzled source chunk (shorts)
        #pragma unroll
        for (int c = 0; c < PW; ++c) {
            int j = wave * PW + c;
            const ushort_t* gt;
            int off, jj, gb;
            if (j < CA)               { gt = Ath; jj = j;              off = 0;      gb = bm; }
            else if (j < 2 * CA)      { gt = Atl; jj = j - CA;         off = AOFF_L; gb = bm; }
            else if (j < 2 * CA + CB) { gt = Bth; jj = j - 2 * CA;     off = BOFF_H; gb = bn; }
            else                      { gt = Btl; jj = j - 2 * CA - CB; off = BOFF_L; gb = bn; }
            gsrc[c] = gt + (size_t)(gb + jj * 16 + rr) * K + sw;
            ldst[c] = off + jj * 512;      // 1KB = 512 shorts per chunk
        }
    }

    // --- fragment read offsets (swizzled) ---
    int aoff[TM], boff[TN];
    #pragma unroll
    for (int tt = 0; tt < TM; ++tt) {
        int r = wm * 16 * TM + tt * 16 + l16;
        aoff[tt] = r * 32 + ((quad ^ (r & 3)) << 3);
    }
    #pragma unroll
    for (int tn = 0; tn < TN; ++tn) {
        int r = wn * 16 * TN + tn * 16 + l16;
        boff[tn] = r * 32 + ((quad ^ (r & 3)) << 3);
    }

    v4f acc[TM][TN];
    #pragma unroll
    for (int i = 0; i < TM; ++i)
        #pragma unroll
        for (int j = 0; j < TN; ++j) acc[i][j] = 0.f;

    // prologue: stage first K-step into buf 0
    #pragma unroll
    for (int c = 0; c < PW; ++c) async_cp16(gsrc[c], &lds[0][ldst[c]]);

    // embedded bucket scatter: rides in the prologue-DMA latency shadow
    if constexpr (SCAT) {
        const int tid0 = (blockIdx.y * gridDim.x + blockIdx.x) * 256 + t;
        const int tots = gridDim.x * gridDim.y * 256;
        for (int e = tid0; e < EE; e += tots) {
            int d = dstE[e];
            int pos = atomicAdd(&cnt[d], 1);
            if (pos < BUCK) eslot[d * BUCK + pos] = srcE[e];
        }
    }

    int cur = 0;
    for (int k0 = 0; k0 < K; k0 += 32) {
        __syncthreads();  // drains vmcnt(0): buf[cur] ready; all reads of buf[cur^1] done
        if (k0 + 32 < K) {
            #pragma unroll
            for (int c = 0; c < PW; ++c)
                async_cp16(gsrc[c] + k0 + 32, &lds[cur ^ 1][ldst[c]]);
        }
        const ushort_t* bufc = lds[cur];
        v8s ah[TM], al2[TM], bh2[TN], bl2[TN];
        #pragma unroll
        for (int tt = 0; tt < TM; ++tt) {
            ah[tt]  = *(const v8s*)&bufc[aoff[tt]];
            al2[tt] = *(const v8s*)&bufc[AOFF_L + aoff[tt]];
        }
        #pragma unroll
        for (int tn = 0; tn < TN; ++tn) {
            bh2[tn] = *(const v8s*)&bufc[BOFF_H + boff[tn]];
            bl2[tn] = *(const v8s*)&bufc[BOFF_L + boff[tn]];
        }
        #pragma unroll
        for (int tm = 0; tm < TM; ++tm)
            #pragma unroll
            for (int tn = 0; tn < TN; ++tn) {
                acc[tm][tn] = __builtin_amdgcn_mfma_f32_16x16x32_bf16(
                    ah[tm], bh2[tn], acc[tm][tn], 0, 0, 0);
                acc[tm][tn] = __builtin_amdgcn_mfma_f32_16x16x32_bf16(
                    ah[tm], bl2[tn], acc[tm][tn], 0, 0, 0);
                acc[tm][tn] = __builtin_amdgcn_mfma_f32_16x16x32_bf16(
                    al2[tm], bh2[tn], acc[tm][tn], 0, 0, 0);
            }
        cur ^= 1;
    }

    // epilogue: C/D layout col=lane&15, row=quad*4+reg
    #pragma unroll
    for (int tm = 0; tm < TM; ++tm) {
        #pragma unroll
        for (int tn = 0; tn < TN; ++tn) {
            int row0 = bm + wm * 16 * TM + tm * 16 + quad * 4;
            int col  = bn + wn * 16 * TN + tn * 16 + l16;
            float badd = BIAS ? bias[col] : 0.f;
            #pragma unroll
            for (int reg = 0; reg < 4; ++reg) {
                int row = row0 + reg;
                if (row < M) {
                    float v = acc[tm][tn][reg] + badd;
                    if (WF32) C[(size_t)row * CS + col] = v;
                    if (WBF) Cbf[(size_t)row * CS + col] = f2bf(v);
                }
            }
        }
    }

    // fused attention scores: head spans 16*TPH contiguous cols
    if constexpr (TPH > 0) {
        constexpr int GR = TN / TPH;
        float aS[TN], aD[TN];
        #pragma unroll
        for (int tn = 0; tn < TN; ++tn) {
            int col = bn + wn * 16 * TN + tn * 16 + l16;
            aS[tn] = att_s[col];
            aD[tn] = att_d[col];
        }
        #pragma unroll
        for (int tm = 0; tm < TM; ++tm) {
            #pragma unroll
            for (int reg = 0; reg < 4; ++reg) {
                #pragma unroll
                for (int g = 0; g < GR; ++g) {
                    float ss = 0.f, sd = 0.f;
                    #pragma unroll
                    for (int ti = 0; ti < TPH; ++ti) {
                        int tn = g * TPH + ti;
                        ss += acc[tm][tn][reg] * aS[tn];
                        sd += acc[tm][tn][reg] * aD[tn];
                    }
                    #pragma unroll
                    for (int off = 1; off < 16; off <<= 1) {
                        ss += __shfl_xor(ss, off);
                        sd += __shfl_xor(sd, off);
                    }
                    if (l16 == 0) {
                        int row = bm + wm * 16 * TM + tm * 16 + quad * 4 + reg;
                        if (row < M) {
                            int head = (bn + wn * 16 * TN + g * 16 * TPH) / (16 * TPH);
                            asrc[row * NH + head] = ss;
                            adst[row * NH + head] = sd;
                        }
                    }
                }
            }
        }
    }
}

// ---------------- unified fused softmax aggregation ----------------
// 1 wave / dst node, CPL channels/lane (row = 64*CPL chans, head = lane>>3).
// Online softmax, depth-1 prefetch over 4-edge groups.
// R7: whole bucket's edge indices loaded in ONE coalesced 64-lane load at wave
// start (lane j holds edge j's src); per-edge index via __shfl -> removes the
// chained index-load -> row-gather latency (2 hops -> 1) in the hot loop.
// Arithmetic order identical to R5 (same groups, same FP ops) -> absmax identical.
// Edge list: padded bucket edge_slot[d*BUCK + j], deg = min(counts[d], BUCK).
// OSPLIT: write split hi/lo bf16.  OF32: write fp32.  PADB: padded bias map.

template <int CPL, bool ELU, bool OSPLIT, bool OF32, bool PADB>
__global__ __launch_bounds__(256) void agg_u(const ushort_t* __restrict__ hb,
                                             const float* __restrict__ asrc,
                                             const float* __restrict__ adst,
                                             const int* __restrict__ counts,
                                             const int* __restrict__ edge_slot,
                                             const float* __restrict__ bias,
                                             float* __restrict__ outf,
                                             ushort_t* __restrict__ outh,
                                             ushort_t* __restrict__ outl,
                                             int n) {
    constexpr int RSB = CPL * 64;
    using VT = typename std::conditional<CPL == 8, u16x8, u16x4v>::type;
    const int d    = (blockIdx.x * blockDim.x + threadIdx.x) >> 6;
    const int lane = threadIdx.x & 63;
    if (d >= n) return;
    const int head = lane >> 3;

    // whole bucket of edge indices in one coalesced load (lane j = edge j)
    const int eidx_reg = edge_slot[d * BUCK + lane];
    const int deg = min(counts[d], BUCK);

    const float adh = (lane < NH) ? adst[d * NH + lane] : 0.f;

    float m, s;
    float ac[CPL];
    {
        float a = (lane < NH) ? asrc[d * NH + lane] + adh : 0.f;
        a = fmaxf(a, 0.2f * a);
        m = a;
        s = 1.f;
        VT u = *(const VT*)(hb + (size_t)d * RSB + CPL * lane);
        #pragma unroll
        for (int i = 0; i < CPL; ++i) ac[i] = bf2f(u[i]);
    }

    auto LD = [&](int j0, VT* rr, float* ss, int* ii) {
        int i0 = __shfl(eidx_reg, j0);
        int i1 = __shfl(eidx_reg, j0 + 1);
        int i2 = __shfl(eidx_reg, j0 + 2);
        int i3 = __shfl(eidx_reg, j0 + 3);
        ii[0] = i0; ii[1] = i1; ii[2] = i2; ii[3] = i3;
        rr[0] = *(const VT*)(hb + (size_t)i0 * RSB + CPL * lane);
        rr[1] = *(const VT*)(hb + (size_t)i1 * RSB + CPL * lane);
        rr[2] = *(const VT*)(hb + (size_t)i2 * RSB + CPL * lane);
        rr[3] = *(const VT*)(hb + (size_t)i3 * RSB + CPL * lane);
        if (lane < NH) {
            ss[0] = asrc[i0 * NH + lane];
            ss[1] = asrc[i1 * NH + lane];
            ss[2] = asrc[i2 * NH + lane];
            ss[3] = asrc[i3 * NH + lane];
        } else {
            ss[0] = ss[1] = ss[2] = ss[3] = 0.f;
        }
    };
    auto PR = [&](const VT* rr, const float* ss) {
        float a0 = ss[0] + adh, a1 = ss[1] + adh, a2 = ss[2] + adh, a3 = ss[3] + adh;
        a0 = fmaxf(a0, 0.2f * a0);
        a1 = fmaxf(a1, 0.2f * a1);
        a2 = fmaxf(a2, 0.2f * a2);
        a3 = fmaxf(a3, 0.2f * a3);
        float mn = fmaxf(m, fmaxf(fmaxf(a0, a1), fmaxf(a2, a3)));
        float al = __expf(m - mn);
        float w0 = __expf(a0 - mn);
        float w1 = __expf(a1 - mn);
        float w2 = __expf(a2 - mn);
        float w3 = __expf(a3 - mn);
        s = s * al + (w0 + w1) + (w2 + w3);
        m = mn;
        float alc = __shfl(al, head);
        float c0 = __shfl(w0, head);
        float c1 = __shfl(w1, head);
        float c2 = __shfl(w2, head);
        float c3 = __shfl(w3, head);
        #pragma unroll
        for (int i = 0; i < CPL; ++i)
            ac[i] = ac[i] * alc + c0 * bf2f(rr[0][i]) + c1 * bf2f(rr[1][i]) +
                    c2 * bf2f(rr[2][i]) + c3 * bf2f(rr[3][i]);
    };

    int j = 0;
    const int ng = deg >> 2;
    if (ng > 0) {
        VT cr[4];
        float cs[4];
        int ci[4];
        LD(0, cr, cs, ci);
        for (int g = 1; g < ng; ++g) {
            VT nr[4];
            float ns[4];
            int ni[4];
            LD(4 * g, nr, ns, ni);
            PR(cr, cs);
            #pragma unroll
            for (int q = 0; q < 4; ++q) { cr[q] = nr[q]; cs[q] = ns[q]; }
        }
        PR(cr, cs);
        j = 4 * ng;
    }
    for (; j < deg; ++j) {
        int i0 = __shfl(eidx_reg, j);
        VT r0 = *(const VT*)(hb + (size_t)i0 * RSB + CPL * lane);
        float a0 = (lane < NH) ? asrc[i0 * NH + lane] + adh : 0.f;
        a0 = fmaxf(a0, 0.2f * a0);
        float mn = fmaxf(m, a0);
        float al = __expf(m - mn);
        float w0 = __expf(a0 - mn);
        s = s * al + w0;
        m = mn;
        float alc = __shfl(al, head);
        float c0w = __shfl(w0, head);
        #pragma unroll
        for (int i = 0; i < CPL; ++i) ac[i] = ac[i] * alc + c0w * bf2f(r0[i]);
    }

    float inv = 1.f / s;
    float ivc = __shfl(inv, head);
    float o[CPL];
    if constexpr (PADB) {
        const int c = CPL * lane;
        const int cc = c & 31;
        const int bbase = (c >> 5) * 30 + cc;
        #pragma unroll
        for (int i = 0; i < CPL; ++i) {
            float b = (cc + i < 30) ? bias[bbase + i] : 0.f;
            o[i] = ac[i] * ivc + b;   // pad channels: 0*ivc + 0 = 0
        }
    } else {
        #pragma unroll
        for (int i = 0; i < CPL; ++i) o[i] = ac[i] * ivc + bias[CPL * lane + i];
    }
    if (ELU) {
        #pragma unroll
        for (int i = 0; i < CPL; ++i) o[i] = (o[i] > 0.f) ? o[i] : __expf(o[i]) - 1.f;
    }
    if constexpr (OSPLIT) {
        VT hh, ll;
        #pragma unroll
        for (int i = 0; i < CPL; ++i) {
            ushort_t h2, l2;
            split1(o[i], h2, l2);
            hh[i] = h2;
            ll[i] = l2;
        }
        *(VT*)(outh + (size_t)d * RSB + CPL * lane) = hh;
        *(VT*)(outl + (size_t)d * RSB + CPL * lane) = ll;
    }
    if constexpr (OF32) {
        float4* orow = (float4*)(outf + (size_t)d * RSB);
        #pragma unroll
        for (int q = 0; q < CPL / 4; ++q) {
            float4 v;
            v.x = o[4 * q + 0];
            v.y = o[4 * q + 1];
            v.z = o[4 * q + 2];
            v.w = o[4 * q + 3];
            orow[(CPL / 4) * lane + q] = v;
        }
    }
}

// ---------------- launch ----------------

extern "C" void kernel_launch(void* const* d_in, const int* in_sizes, int n_in,
                              void* d_out, int out_size, void* d_ws, size_t ws_size,
                              hipStream_t stream) {
    const float* x      = (const float*)d_in[0];
    const int*   eidx   = (const int*)d_in[1];   // [2, E]
    const float* W1     = (const float*)d_in[2];
    const float* a1_src = (const float*)d_in[3];
    const float* a1_dst = (const float*)d_in[4];
    const float* b1     = (const float*)d_in[5];
    const float* W2     = (const float*)d_in[6];
    const float* a2_src = (const float*)d_in[7];
    const float* a2_dst = (const float*)d_in[8];
    const float* b2     = (const float*)d_in[9];
    const float* Wlin   = (const float*)d_in[10];
    const float* blin   = (const float*)d_in[11];

    const int* src = eidx;        // row 0
    const int* dst = eidx + EE;   // row 1

    float* out0  = (float*)d_out;                      // [N, NCLS]
    float* h_out = (float*)d_out + (size_t)NN * NCLS;  // [N, HC2] (output 1)

    // workspace layout: floats, then ushorts, then ints
    float* f = (float*)d_ws;
    float* asrc1 = f;
    float* adst1 = asrc1 + NN * NH;
    float* asrc2 = adst1 + NN * NH;
    float* adst2 = asrc2 + NN * NH;
    float* a1sP  = adst2 + NN * NH;          // [HC1P]
    float* a1dP  = a1sP + HC1P;              // [HC1P]
    ushort_t* xh    = (ushort_t*)(a1dP + HC1P);        // [NP][FIN] hi
    ushort_t* xl    = xh + (size_t)NP * FIN;           // [NP][FIN] lo
    ushort_t* w1t_h = xl + (size_t)NP * FIN;
    ushort_t* w1t_l = w1t_h + TS1;
    ushort_t* w2t_h = w1t_l + TS1;
    ushort_t* w2t_l = w2t_h + TS2;
    ushort_t* wlt_h = w2t_l + TS2;
    ushort_t* wlt_l = wlt_h + TS3;
    ushort_t* h1p_bf = wlt_l + TS3;                    // [NN][HC1P] bf16 (pre-agg)
    ushort_t* h1h    = h1p_bf + (size_t)NN * HC1P;     // [NP][HC1P] hi (post-agg)
    ushort_t* h1l    = h1h + (size_t)NP * HC1P;        // [NP][HC1P] lo
    ushort_t* h2p_bf = h1l + (size_t)NP * HC1P;        // [NN][HC2] bf16 (pre-agg)
    ushort_t* h2h    = h2p_bf + (size_t)NN * HC2;      // [NP][HC2] hi (post-agg)
    ushort_t* h2l    = h2h + (size_t)NP * HC2;         // [NP][HC2] lo
    int* counts    = (int*)(h2l + (size_t)NP * HC2);   // [NN] degree/cursor
    int* edge_slot = counts + NN;                      // [NN*BUCK] padded buckets

    // prep: zero counts + x split + transposes/splits + padded a1 vectors
    {
        const int total = XS + TS1 + TS2 + TS3 + 2 * HC1P;
        prep_kernel<<<(total + 255) / 256, 256, 0, stream>>>(
            x, W1, W2, Wlin, a1_src, a1_dst, xh, xl, w1t_h, w1t_l,
            w2t_h, w2t_l, wlt_h, wlt_l, a1sP, a1dP, counts);
    }

    const int MB = (NN + 63) / 64;  // 157

    // Layer 1: 64x128 tiles -> grid(157,2) + fused att1 + EMBEDDED bucket scatter
    {
        dim3 grid(MB, HC1P / 128);
        gemm_mfma<2, 4, false, false, true, 2, true><<<grid, 256, 0, stream>>>(
            xh, xl, w1t_h, w1t_l, nullptr, nullptr, h1p_bf,
            a1sP, a1dP, asrc1, adst1, src, dst, counts, edge_slot,
            NN, FIN, HC1P);
    }
    // agg1: 4 ch/lane, ELU, writes split hi/lo bf16 h1
    agg_u<4, true, true, false, true><<<(NN + 3) / 4, 256, 0, stream>>>(
        h1p_bf, asrc1, adst1, counts, edge_slot, b1, nullptr, h1h, h1l, NN);

    // Layer 2: 64x128 tiles -> grid(157,4) + fused att2 (head = 64 cols)
    {
        dim3 grid(MB, HC2 / 128);
        gemm_mfma<2, 4, false, false, true, 4, false><<<grid, 256, 0, stream>>>(
            h1h, h1l, w2t_h, w2t_l, nullptr, nullptr, h2p_bf,
            a2_src, a2_dst, asrc2, adst2, nullptr, nullptr, nullptr, nullptr,
            NN, HC1P, HC2);
    }
    // agg2: 8 ch/lane, no ELU, writes fp32 h_out (output 1) + split hi/lo for head GEMM
    agg_u<8, false, true, true, false><<<(NN + 3) / 4, 256, 0, stream>>>(
        h2p_bf, asrc2, adst2, counts, edge_slot, b2, h_out, h2h, h2l, NN);

    // Head: 32x64 tiles -> grid(313,1)
    {
        dim3 grid((NN + 31) / 32, NCLS / 64);
        gemm_mfma<1, 2, true, true, false, 0, false><<<grid, 256, 0, stream>>>(
            h2h, h2l, wlt_h, wlt_l, blin, out0, nullptr,
            nullptr, nullptr, nullptr, nullptr, nullptr, nullptr, nullptr, nullptr,
            NN, HC2, NCLS);
    }
}